// Round 1
// baseline (3125.223 us; speedup 1.0000x reference)
//
#include <hip/hip_runtime.h>
#include <math.h>

#define BATCH 16
#define GRID  80
#define NANCH 3
#define KTOP  300
#define NBOX  (NANCH*GRID*GRID)   // 19200

__device__ __forceinline__ float sigmoidf_(float x){ return 1.0f/(1.0f+expf(-x)); }

// ---------------- 3x3 stride-2 conv + SiLU, NCHW, SAME pad = (0,1) ----------------
template<int CIN, int COUT, int HIN, int HOUT>
__global__ __launch_bounds__(256) void conv3x3s2_silu(
    const float* __restrict__ in, const float* __restrict__ w,
    const float* __restrict__ bias, float* __restrict__ out)
{
  int idx = blockIdx.x*256 + threadIdx.x;
  const int total = BATCH*COUT*HOUT*HOUT;
  if (idx >= total) return;
  int ox = idx % HOUT;
  int oy = (idx / HOUT) % HOUT;
  int oc = (idx / (HOUT*HOUT)) % COUT;
  int b  = idx / (HOUT*HOUT*COUT);
  const float* inb = in + (size_t)b*CIN*HIN*HIN;
  float acc = bias[oc];
  const int iy0 = oy*2, ix0 = ox*2;
  for (int ic=0; ic<CIN; ++ic){
    const float* inc = inb + (size_t)ic*HIN*HIN;
    const float* wc  = w + ((size_t)oc*CIN + ic)*9;
    #pragma unroll
    for (int ky=0; ky<3; ++ky){
      int iy = iy0+ky;
      if (iy < HIN){
        const float* row = inc + (size_t)iy*HIN;
        #pragma unroll
        for (int kx=0; kx<3; ++kx){
          int ix = ix0+kx;
          if (ix < HIN) acc += row[ix]*wc[ky*3+kx];
        }
      }
    }
  }
  float sg = 1.0f/(1.0f+expf(-acc));
  out[idx] = acc * sg;
}

// ---------------- 1x1 head (only the 6 needed channels) + sigmoid + decode ----------------
__global__ __launch_bounds__(256) void decode_kernel(
    const float* __restrict__ f3, const float* __restrict__ Wh,
    const float* __restrict__ bh, float* __restrict__ boxes,
    float* __restrict__ scores)
{
  int idx = blockIdx.x*256 + threadIdx.x;
  const int total = BATCH*NANCH*GRID*GRID;
  if (idx >= total) return;
  int gx = idx % GRID;
  int gy = (idx/GRID)%GRID;
  int a  = (idx/(GRID*GRID))%NANCH;
  int b  = idx/(GRID*GRID*NANCH);
  const float aw[3] = {4.0f, 8.0f, 13.0f};
  const float ah[3] = {5.0f, 10.0f, 16.0f};
  const int   chs[6] = {0,1,2,3,4,15};
  const float* f = f3 + (size_t)b*64*GRID*GRID + (size_t)gy*GRID + gx;
  float acc[6];
  #pragma unroll
  for (int j=0;j<6;j++) acc[j] = bh[a*16 + chs[j]];
  for (int ic=0; ic<64; ++ic){
    float v = f[(size_t)ic*GRID*GRID];
    #pragma unroll
    for (int j=0;j<6;j++) acc[j] += v * Wh[(size_t)(a*16+chs[j])*64 + ic];
  }
  float p0 = sigmoidf_(acc[0]);
  float p1 = sigmoidf_(acc[1]);
  float p2 = sigmoidf_(acc[2]);
  float p3 = sigmoidf_(acc[3]);
  float p4 = sigmoidf_(acc[4]);
  float p15= sigmoidf_(acc[5]);
  float cx = (p0*2.0f - 0.5f + (float)gx)*8.0f;
  float cy = (p1*2.0f - 0.5f + (float)gy)*8.0f;
  float ww = p2*2.0f; ww = ww*ww*aw[a];
  float hh = p3*2.0f; hh = hh*hh*ah[a];
  float sc = p4*p15;
  sc = (sc > 0.5f) ? sc : 0.0f;
  int bi = a*GRID*GRID + gy*GRID + gx;
  float* bo = boxes + ((size_t)b*NBOX + bi)*4;
  bo[0] = cx - ww*0.5f;
  bo[1] = cy - hh*0.5f;
  bo[2] = cx + ww*0.5f;
  bo[3] = cy + hh*0.5f;
  scores[(size_t)b*NBOX + bi] = sc;
}

// ---------------- exact top-K (stable, ties -> lowest index) + greedy NMS ----------------
__global__ __launch_bounds__(1024) void topk_nms_kernel(
    const float* __restrict__ boxes, const float* __restrict__ scores,
    float* __restrict__ out)
{
  __shared__ float s[NBOX];          // 76.8 KB
  __shared__ int   sel[KTOP];
  __shared__ float selsc[KTOP];
  __shared__ float bx[KTOP][4];
  __shared__ float area[KTOP];
  __shared__ int   keep[KTOP];
  __shared__ float rs[16];
  __shared__ int   ri[16];
  const int b = blockIdx.x;
  const int t = threadIdx.x;
  const float* scp = scores + (size_t)b*NBOX;
  for (int i=t;i<NBOX;i+=1024) s[i] = scp[i];
  __syncthreads();

  // 300 argmax passes; strict > in the rising-index per-thread scan keeps
  // the earliest index on ties => matches lax.top_k stable order exactly.
  for (int k=0;k<KTOP;k++){
    float best = -2.0f; int bi = NBOX;
    for (int i=t;i<NBOX;i+=1024){
      float v = s[i];
      if (v > best){ best=v; bi=i; }
    }
    #pragma unroll
    for (int off=32; off>0; off>>=1){
      float ov = __shfl_down(best, off);
      int   oi = __shfl_down(bi,   off);
      if (ov > best || (ov == best && oi < bi)){ best=ov; bi=oi; }
    }
    if ((t & 63) == 0){ rs[t>>6]=best; ri[t>>6]=bi; }
    __syncthreads();
    if (t == 0){
      for (int wv=1; wv<16; wv++){
        if (rs[wv] > best || (rs[wv] == best && ri[wv] < bi)){ best=rs[wv]; bi=ri[wv]; }
      }
      sel[k]=bi; selsc[k]=best; s[bi] = -1.0f;
    }
    __syncthreads();
  }

  // gather boxes for the selected 300 (regardless of score — reference does)
  if (t < KTOP){
    const float* bp = boxes + ((size_t)b*NBOX + sel[t])*4;
    float x1=bp[0], y1=bp[1], x2=bp[2], y2=bp[3];
    bx[t][0]=x1; bx[t][1]=y1; bx[t][2]=x2; bx[t][3]=y2;
    area[t] = fmaxf(x2-x1,0.0f)*fmaxf(y2-y1,0.0f);
    keep[t] = 1;
  }
  __syncthreads();

  // greedy NMS: sequential over i, parallel over j>i
  for (int i=0;i<KTOP;i++){
    int ki = keep[i];
    if (ki && t > i && t < KTOP){
      float ix1=fmaxf(bx[i][0],bx[t][0]);
      float iy1=fmaxf(bx[i][1],bx[t][1]);
      float ix2=fminf(bx[i][2],bx[t][2]);
      float iy2=fminf(bx[i][3],bx[t][3]);
      float inter=fmaxf(ix2-ix1,0.0f)*fmaxf(iy2-iy1,0.0f);
      float iou = inter/(area[i]+area[t]-inter+1e-7f);
      if (iou > 0.5f) keep[t]=0;
    }
    __syncthreads();
  }

  if (t < KTOP){
    float scv = selsc[t];
    float kf  = (keep[t] && scv > 0.0f) ? 1.0f : 0.0f;
    float* o = out + ((size_t)b*KTOP + t)*6;
    o[0]=bx[t][0]; o[1]=bx[t][1]; o[2]=bx[t][2]; o[3]=bx[t][3];
    o[4]=scv; o[5]=kf;
  }
}

extern "C" void kernel_launch(void* const* d_in, const int* in_sizes, int n_in,
                              void* d_out, int out_size, void* d_ws, size_t ws_size,
                              hipStream_t stream) {
  const float* x  = (const float*)d_in[0];
  const float* W1 = (const float*)d_in[1];
  const float* b1 = (const float*)d_in[2];
  const float* W2 = (const float*)d_in[3];
  const float* b2 = (const float*)d_in[4];
  const float* W3 = (const float*)d_in[5];
  const float* b3 = (const float*)d_in[6];
  const float* Wh = (const float*)d_in[7];
  const float* bh = (const float*)d_in[8];
  float* out = (float*)d_out;
  float* ws  = (float*)d_ws;

  // workspace layout (floats):
  // f1: [0, 26,214,400)            16x16x320x320
  // f2: [26,214,400, 39,321,600)   16x32x160x160
  // f3: reuses f1 region           16x64x80x80   (6,553,600)
  // boxes: reuses f2 region        16x19200x4    (1,228,800)
  // scores: after boxes            16x19200      (307,200)
  float* f1     = ws;
  float* f2     = ws + 26214400;
  float* f3     = ws;               // overwrite f1 (no longer needed)
  float* boxes  = ws + 26214400;    // overwrite f2 (after conv3)
  float* scores = boxes + 1228800;

  conv3x3s2_silu<3,16,640,320><<<(16*16*320*320+255)/256, 256, 0, stream>>>(x,  W1, b1, f1);
  conv3x3s2_silu<16,32,320,160><<<(16*32*160*160+255)/256, 256, 0, stream>>>(f1, W2, b2, f2);
  conv3x3s2_silu<32,64,160,80><<<(16*64*80*80+255)/256, 256, 0, stream>>>(f2, W3, b3, f3);
  decode_kernel<<<(BATCH*NANCH*GRID*GRID+255)/256, 256, 0, stream>>>(f3, Wh, bh, boxes, scores);
  topk_nms_kernel<<<BATCH, 1024, 0, stream>>>(boxes, scores, out);
}

// Round 2
// 1394.069 us; speedup vs baseline: 2.2418x; 2.2418x over previous
//
#include <hip/hip_runtime.h>
#include <math.h>

#define BATCH 16
#define GRID  80
#define NANCH 3
#define KTOP  300
#define NBOX  (NANCH*GRID*GRID)   // 19200

__device__ __forceinline__ float sigmoidf_(float x){ return 1.0f/(1.0f+expf(-x)); }

// ---------------- tiled 3x3 stride-2 conv + SiLU ----------------
// block = 256 threads = 16x16 output tile. Stage input halo (33x33 per ch,
// IC_CHUNK channels) in LDS; each thread holds COUT_TILE accumulators so one
// LDS read feeds COUT_TILE FMAs; weights are wave-uniform -> SGPR loads.
template<int CIN, int COUT, int COUT_TILE, int IC_CHUNK, int HIN, int HOUT>
__global__ __launch_bounds__(256) void conv3x3s2_tiled(
    const float* __restrict__ in, const float* __restrict__ w,
    const float* __restrict__ bias, float* __restrict__ out)
{
  constexpr int TILES = HOUT/16;
  constexpr int TE = 33*33; // 1089 elements per channel tile
  __shared__ float lds[IC_CHUNK*TE];
  const int t  = threadIdx.x;
  const int tx = t & 15, ty = t >> 4;
  int blk = blockIdx.x;
  const int bx = blk % TILES; blk /= TILES;
  const int by = blk % TILES; blk /= TILES;
  const int b  = blk % BATCH; blk /= BATCH;
  const int ocg= blk;
  const int ox = bx*16 + tx, oy = by*16 + ty;
  const int ix0 = bx*32, iy0 = by*32;

  float acc[COUT_TILE];
  #pragma unroll
  for (int oc=0; oc<COUT_TILE; ++oc) acc[oc] = bias[ocg*COUT_TILE+oc];

  for (int c0=0; c0<CIN; c0+=IC_CHUNK){
    __syncthreads();
    for (int i=t; i<IC_CHUNK*TE; i+=256){
      int c = i/TE, r = i - c*TE;
      int yy = r/33, xx = r - yy*33;
      int iy = iy0+yy, ix = ix0+xx;
      float v = 0.0f;
      if (iy < HIN && ix < HIN)
        v = in[((size_t)(b*CIN + c0+c)*HIN + iy)*HIN + ix];
      lds[i] = v;
    }
    __syncthreads();
    for (int ic=0; ic<IC_CHUNK; ++ic){
      const float* lp = lds + ic*TE + (2*ty)*33 + 2*tx;
      float v[9];
      #pragma unroll
      for (int ky=0;ky<3;ky++)
        #pragma unroll
        for (int kx=0;kx<3;kx++)
          v[ky*3+kx] = lp[ky*33+kx];
      const float* wp = w + ((size_t)(ocg*COUT_TILE)*CIN + (c0+ic))*9;
      #pragma unroll
      for (int oc=0; oc<COUT_TILE; ++oc){
        const float* wo = wp + (size_t)oc*CIN*9;
        #pragma unroll
        for (int k=0;k<9;k++)
          acc[oc] += v[k]*wo[k];
      }
    }
  }

  #pragma unroll
  for (int oc=0; oc<COUT_TILE; ++oc){
    float z = acc[oc];
    float s = 1.0f/(1.0f+expf(-z));
    out[((size_t)(b*COUT + ocg*COUT_TILE+oc)*HOUT + oy)*HOUT + ox] = z*s;
  }
}

// ---------------- 1x1 head (only the 6 needed channels) + sigmoid + decode ----------------
__global__ __launch_bounds__(256) void decode_kernel(
    const float* __restrict__ f3, const float* __restrict__ Wh,
    const float* __restrict__ bh, float* __restrict__ boxes,
    float* __restrict__ scores)
{
  int idx = blockIdx.x*256 + threadIdx.x;
  const int total = BATCH*NANCH*GRID*GRID;
  if (idx >= total) return;
  int gx = idx % GRID;
  int gy = (idx/GRID)%GRID;
  int a  = (idx/(GRID*GRID))%NANCH;
  int b  = idx/(GRID*GRID*NANCH);
  const float aw[3] = {4.0f, 8.0f, 13.0f};
  const float ah[3] = {5.0f, 10.0f, 16.0f};
  const int   chs[6] = {0,1,2,3,4,15};
  const float* f = f3 + (size_t)b*64*GRID*GRID + (size_t)gy*GRID + gx;
  float acc[6];
  #pragma unroll
  for (int j=0;j<6;j++) acc[j] = bh[a*16 + chs[j]];
  for (int ic=0; ic<64; ++ic){
    float v = f[(size_t)ic*GRID*GRID];
    #pragma unroll
    for (int j=0;j<6;j++) acc[j] += v * Wh[(size_t)(a*16+chs[j])*64 + ic];
  }
  float p0 = sigmoidf_(acc[0]);
  float p1 = sigmoidf_(acc[1]);
  float p2 = sigmoidf_(acc[2]);
  float p3 = sigmoidf_(acc[3]);
  float p4 = sigmoidf_(acc[4]);
  float p15= sigmoidf_(acc[5]);
  float cx = (p0*2.0f - 0.5f + (float)gx)*8.0f;
  float cy = (p1*2.0f - 0.5f + (float)gy)*8.0f;
  float ww = p2*2.0f; ww = ww*ww*aw[a];
  float hh = p3*2.0f; hh = hh*hh*ah[a];
  float sc = p4*p15;
  sc = (sc > 0.5f) ? sc : 0.0f;
  int bi = a*GRID*GRID + gy*GRID + gx;
  float* bo = boxes + ((size_t)b*NBOX + bi)*4;
  bo[0] = cx - ww*0.5f;
  bo[1] = cy - hh*0.5f;
  bo[2] = cx + ww*0.5f;
  bo[3] = cy + hh*0.5f;
  scores[(size_t)b*NBOX + bi] = sc;
}

// ---------------- exact top-K (stable, ties -> lowest index) + greedy NMS ----------------
__global__ __launch_bounds__(1024) void topk_nms_kernel(
    const float* __restrict__ boxes, const float* __restrict__ scores,
    float* __restrict__ out)
{
  __shared__ float s[NBOX];          // 76.8 KB
  __shared__ int   sel[KTOP];
  __shared__ float selsc[KTOP];
  __shared__ float bx[KTOP][4];
  __shared__ float area[KTOP];
  __shared__ int   keep[KTOP];
  __shared__ float rs[16];
  __shared__ int   ri[16];
  const int b = blockIdx.x;
  const int t = threadIdx.x;
  const float* scp = scores + (size_t)b*NBOX;
  for (int i=t;i<NBOX;i+=1024) s[i] = scp[i];
  __syncthreads();

  for (int k=0;k<KTOP;k++){
    float best = -2.0f; int bi = NBOX;
    for (int i=t;i<NBOX;i+=1024){
      float v = s[i];
      if (v > best){ best=v; bi=i; }
    }
    #pragma unroll
    for (int off=32; off>0; off>>=1){
      float ov = __shfl_down(best, off);
      int   oi = __shfl_down(bi,   off);
      if (ov > best || (ov == best && oi < bi)){ best=ov; bi=oi; }
    }
    if ((t & 63) == 0){ rs[t>>6]=best; ri[t>>6]=bi; }
    __syncthreads();
    if (t == 0){
      for (int wv=1; wv<16; wv++){
        if (rs[wv] > best || (rs[wv] == best && ri[wv] < bi)){ best=rs[wv]; bi=ri[wv]; }
      }
      sel[k]=bi; selsc[k]=best; s[bi] = -1.0f;
    }
    __syncthreads();
  }

  if (t < KTOP){
    const float* bp = boxes + ((size_t)b*NBOX + sel[t])*4;
    float x1=bp[0], y1=bp[1], x2=bp[2], y2=bp[3];
    bx[t][0]=x1; bx[t][1]=y1; bx[t][2]=x2; bx[t][3]=y2;
    area[t] = fmaxf(x2-x1,0.0f)*fmaxf(y2-y1,0.0f);
    keep[t] = 1;
  }
  __syncthreads();

  for (int i=0;i<KTOP;i++){
    int ki = keep[i];
    if (ki && t > i && t < KTOP){
      float ix1=fmaxf(bx[i][0],bx[t][0]);
      float iy1=fmaxf(bx[i][1],bx[t][1]);
      float ix2=fminf(bx[i][2],bx[t][2]);
      float iy2=fminf(bx[i][3],bx[t][3]);
      float inter=fmaxf(ix2-ix1,0.0f)*fmaxf(iy2-iy1,0.0f);
      float iou = inter/(area[i]+area[t]-inter+1e-7f);
      if (iou > 0.5f) keep[t]=0;
    }
    __syncthreads();
  }

  if (t < KTOP){
    float scv = selsc[t];
    float kf  = (keep[t] && scv > 0.0f) ? 1.0f : 0.0f;
    float* o = out + ((size_t)b*KTOP + t)*6;
    o[0]=bx[t][0]; o[1]=bx[t][1]; o[2]=bx[t][2]; o[3]=bx[t][3];
    o[4]=scv; o[5]=kf;
  }
}

extern "C" void kernel_launch(void* const* d_in, const int* in_sizes, int n_in,
                              void* d_out, int out_size, void* d_ws, size_t ws_size,
                              hipStream_t stream) {
  const float* x  = (const float*)d_in[0];
  const float* W1 = (const float*)d_in[1];
  const float* b1 = (const float*)d_in[2];
  const float* W2 = (const float*)d_in[3];
  const float* b2 = (const float*)d_in[4];
  const float* W3 = (const float*)d_in[5];
  const float* b3 = (const float*)d_in[6];
  const float* Wh = (const float*)d_in[7];
  const float* bh = (const float*)d_in[8];
  float* out = (float*)d_out;
  float* ws  = (float*)d_ws;

  float* f1     = ws;               // 16x16x320x320 = 26,214,400
  float* f2     = ws + 26214400;    // 16x32x160x160 = 13,107,200
  float* f3     = ws;               // reuse f1: 16x64x80x80 = 6,553,600
  float* boxes  = ws + 26214400;    // reuse f2: 16x19200x4
  float* scores = boxes + 1228800;  // 16x19200

  // conv1: 3->16, 640->320.  tiles 20x20, 1 oc group
  conv3x3s2_tiled<3,16,16,3,640,320><<<20*20*BATCH*1, 256, 0, stream>>>(x,  W1, b1, f1);
  // conv2: 16->32, 320->160. tiles 10x10, 1 oc group, 2 ic chunks
  conv3x3s2_tiled<16,32,32,8,320,160><<<10*10*BATCH*1, 256, 0, stream>>>(f1, W2, b2, f2);
  // conv3: 32->64, 160->80.  tiles 5x5, 2 oc groups, 4 ic chunks
  conv3x3s2_tiled<32,64,32,8,160,80><<<5*5*BATCH*2, 256, 0, stream>>>(f2, W3, b3, f3);

  decode_kernel<<<(BATCH*NANCH*GRID*GRID+255)/256, 256, 0, stream>>>(f3, Wh, bh, boxes, scores);
  topk_nms_kernel<<<BATCH, 1024, 0, stream>>>(boxes, scores, out);
}

// Round 3
// 746.791 us; speedup vs baseline: 4.1849x; 1.8667x over previous
//
#include <hip/hip_runtime.h>
#include <math.h>

#define BATCH 16
#define GRID  80
#define NANCH 3
#define KTOP  300
#define NBOX  (NANCH*GRID*GRID)   // 19200
#define SORT_CAP 8192

__device__ __forceinline__ float sigmoidf_(float x){ return 1.0f/(1.0f+expf(-x)); }

// ---------------- tiled 3x3 stride-2 conv + SiLU ----------------
template<int CIN, int COUT, int COUT_TILE, int IC_CHUNK, int HIN, int HOUT>
__global__ __launch_bounds__(256) void conv3x3s2_tiled(
    const float* __restrict__ in, const float* __restrict__ w,
    const float* __restrict__ bias, float* __restrict__ out)
{
  constexpr int TILES = HOUT/16;
  constexpr int TE = 33*33; // 1089 elements per channel tile
  __shared__ float lds[IC_CHUNK*TE];
  const int t  = threadIdx.x;
  const int tx = t & 15, ty = t >> 4;
  int blk = blockIdx.x;
  const int bx = blk % TILES; blk /= TILES;
  const int by = blk % TILES; blk /= TILES;
  const int b  = blk % BATCH; blk /= BATCH;
  const int ocg= blk;
  const int ox = bx*16 + tx, oy = by*16 + ty;
  const int ix0 = bx*32, iy0 = by*32;

  float acc[COUT_TILE];
  #pragma unroll
  for (int oc=0; oc<COUT_TILE; ++oc) acc[oc] = bias[ocg*COUT_TILE+oc];

  for (int c0=0; c0<CIN; c0+=IC_CHUNK){
    __syncthreads();
    for (int i=t; i<IC_CHUNK*TE; i+=256){
      int c = i/TE, r = i - c*TE;
      int yy = r/33, xx = r - yy*33;
      int iy = iy0+yy, ix = ix0+xx;
      float v = 0.0f;
      if (iy < HIN && ix < HIN)
        v = in[((size_t)(b*CIN + c0+c)*HIN + iy)*HIN + ix];
      lds[i] = v;
    }
    __syncthreads();
    for (int ic=0; ic<IC_CHUNK; ++ic){
      const float* lp = lds + ic*TE + (2*ty)*33 + 2*tx;
      float v[9];
      #pragma unroll
      for (int ky=0;ky<3;ky++)
        #pragma unroll
        for (int kx=0;kx<3;kx++)
          v[ky*3+kx] = lp[ky*33+kx];
      const float* wp = w + ((size_t)(ocg*COUT_TILE)*CIN + (c0+ic))*9;
      #pragma unroll
      for (int oc=0; oc<COUT_TILE; ++oc){
        const float* wo = wp + (size_t)oc*CIN*9;
        #pragma unroll
        for (int k=0;k<9;k++)
          acc[oc] += v[k]*wo[k];
      }
    }
  }

  #pragma unroll
  for (int oc=0; oc<COUT_TILE; ++oc){
    float z = acc[oc];
    float s = 1.0f/(1.0f+expf(-z));
    out[((size_t)(b*COUT + ocg*COUT_TILE+oc)*HOUT + oy)*HOUT + ox] = z*s;
  }
}

// ---------------- 1x1 head (6 needed channels) + sigmoid + decode ----------------
__global__ __launch_bounds__(256) void decode_kernel(
    const float* __restrict__ f3, const float* __restrict__ Wh,
    const float* __restrict__ bh, float* __restrict__ boxes,
    float* __restrict__ scores)
{
  int idx = blockIdx.x*256 + threadIdx.x;
  const int total = BATCH*NANCH*GRID*GRID;
  if (idx >= total) return;
  int gx = idx % GRID;
  int gy = (idx/GRID)%GRID;
  int a  = (idx/(GRID*GRID))%NANCH;
  int b  = idx/(GRID*GRID*NANCH);
  const float aw[3] = {4.0f, 8.0f, 13.0f};
  const float ah[3] = {5.0f, 10.0f, 16.0f};
  const int   chs[6] = {0,1,2,3,4,15};
  const float* f = f3 + (size_t)b*64*GRID*GRID + (size_t)gy*GRID + gx;
  float acc[6];
  #pragma unroll
  for (int j=0;j<6;j++) acc[j] = bh[a*16 + chs[j]];
  for (int ic=0; ic<64; ++ic){
    float v = f[(size_t)ic*GRID*GRID];
    #pragma unroll
    for (int j=0;j<6;j++) acc[j] += v * Wh[(size_t)(a*16+chs[j])*64 + ic];
  }
  float p0 = sigmoidf_(acc[0]);
  float p1 = sigmoidf_(acc[1]);
  float p2 = sigmoidf_(acc[2]);
  float p3 = sigmoidf_(acc[3]);
  float p4 = sigmoidf_(acc[4]);
  float p15= sigmoidf_(acc[5]);
  float cx = (p0*2.0f - 0.5f + (float)gx)*8.0f;
  float cy = (p1*2.0f - 0.5f + (float)gy)*8.0f;
  float ww = p2*2.0f; ww = ww*ww*aw[a];
  float hh = p3*2.0f; hh = hh*hh*ah[a];
  float sc = p4*p15;
  sc = (sc > 0.5f) ? sc : 0.0f;
  int bi = a*GRID*GRID + gy*GRID + gx;
  float* bo = boxes + ((size_t)b*NBOX + bi)*4;
  bo[0] = cx - ww*0.5f;
  bo[1] = cy - hh*0.5f;
  bo[2] = cx + ww*0.5f;
  bo[3] = cy + hh*0.5f;
  scores[(size_t)b*NBOX + bi] = sc;
}

// ---------------- compact + bitonic-sort top-K + single-wave NMS ----------------
__global__ __launch_bounds__(1024) void topk_nms_kernel(
    const float* __restrict__ boxes, const float* __restrict__ scores,
    float* __restrict__ out)
{
  __shared__ unsigned long long keys[SORT_CAP];  // 64 KB
  __shared__ int   cntM;
  __shared__ int   sel[KTOP];
  __shared__ float selsc[KTOP];
  __shared__ float bxl[KTOP][4];
  __shared__ float areal[KTOP];
  __shared__ int   wsum[16];
  __shared__ float rs[16];
  __shared__ int   ri[16];
  __shared__ unsigned clm[(NBOX+31)/32];         // fallback claimed bitmask

  const int b = blockIdx.x;
  const int t = threadIdx.x;
  const int lane = t & 63, wv = t >> 6;
  const float* scp = scores + (size_t)b*NBOX;

  if (t == 0) cntM = 0;
  __syncthreads();

  // ---- compact positives into packed keys: (score_bits<<32) | ~idx ----
  for (int i=t; i<NBOX; i+=1024){
    float v = scp[i];
    if (v > 0.0f){
      int p = atomicAdd(&cntM, 1);
      if (p < SORT_CAP)
        keys[p] = ((unsigned long long)__float_as_uint(v) << 32)
                | (unsigned)(0xFFFFFFFFu - (unsigned)i);
    }
  }
  __syncthreads();
  const int M = cntM;

  if (M <= SORT_CAP){
    // ---- pad to power of two and bitonic-sort DESCENDING ----
    int P = 64; while (P < M) P <<= 1;
    for (int i=t; i<P; i+=1024) if (i >= M) keys[i] = 0ULL;
    __syncthreads();
    for (int k=2; k<=P; k<<=1){
      for (int j=k>>1; j>0; j>>=1){
        for (int i=t; i<P; i+=1024){
          int ixj = i ^ j;
          if (ixj > i){
            unsigned long long a = keys[i], c = keys[ixj];
            bool up = ((i & k) == 0);        // up-blocks: descending
            if (up ? (a < c) : (a > c)){ keys[i] = c; keys[ixj] = a; }
          }
        }
        __syncthreads();
      }
    }
    const int top = (M < KTOP) ? M : KTOP;
    if (t < top){
      unsigned long long kk = keys[t];
      selsc[t] = __uint_as_float((unsigned)(kk >> 32));
      sel[t]   = (int)(0xFFFFFFFFu - (unsigned)(kk & 0xFFFFFFFFu));
    }
    // ---- zero-fill: first (KTOP-M) zero-score indices, ascending ----
    if (M < KTOP){
      const int need = KTOP - M;
      const int C = (NBOX + 1023)/1024;   // 19
      int lo = t*C, hi = lo+C; if (hi > NBOX) hi = NBOX; if (lo > NBOX) lo = NBOX;
      int zc = 0;
      for (int i=lo;i<hi;i++) if (scp[i] <= 0.0f) zc++;
      int v = zc;
      #pragma unroll
      for (int off=1; off<64; off<<=1){
        int n = __shfl_up(v, off);
        if (lane >= off) v += n;
      }
      if (lane == 63) wsum[wv] = v;
      __syncthreads();
      if (t == 0){
        int a = 0;
        for (int w=0; w<16; w++){ int tmp = wsum[w]; wsum[w] = a; a += tmp; }
      }
      __syncthreads();
      int r = wsum[wv] + v - zc;          // exclusive prefix for this thread
      for (int i=lo;i<hi;i++){
        if (scp[i] <= 0.0f){
          if (r < need){ sel[M+r] = i; selsc[M+r] = 0.0f; }
          r++;
        }
      }
    }
    __syncthreads();
  } else {
    // ---- fallback (M > SORT_CAP): exact argmax passes with claimed bitmask ----
    for (int i=t; i<(NBOX+31)/32; i+=1024) clm[i] = 0u;
    __syncthreads();
    for (int k=0;k<KTOP;k++){
      float best = -2.0f; int bi = NBOX;
      for (int i=t;i<NBOX;i+=1024){
        if (!((clm[i>>5] >> (i&31)) & 1u)){
          float v = scp[i];
          if (v > best){ best=v; bi=i; }
        }
      }
      #pragma unroll
      for (int off=32; off>0; off>>=1){
        float ov = __shfl_down(best, off);
        int   oi = __shfl_down(bi,   off);
        if (ov > best || (ov == best && oi < bi)){ best=ov; bi=oi; }
      }
      if (lane == 0){ rs[wv]=best; ri[wv]=bi; }
      __syncthreads();
      if (t == 0){
        for (int w=1; w<16; w++)
          if (rs[w] > best || (rs[w] == best && ri[w] < bi)){ best=rs[w]; bi=ri[w]; }
        sel[k]=bi; selsc[k]=best; clm[bi>>5] |= (1u << (bi&31));
      }
      __syncthreads();
    }
  }

  // ---- gather boxes + areas ----
  if (t < KTOP){
    const float* bp = boxes + ((size_t)b*NBOX + sel[t])*4;
    float x1=bp[0], y1=bp[1], x2=bp[2], y2=bp[3];
    bxl[t][0]=x1; bxl[t][1]=y1; bxl[t][2]=x2; bxl[t][3]=y2;
    areal[t] = fmaxf(x2-x1,0.0f)*fmaxf(y2-y1,0.0f);
  }
  __syncthreads();

  // ---- greedy NMS in wave 0 only: registers + shuffles, zero barriers ----
  if (t < 64){
    float X1[5],Y1[5],X2[5],Y2[5],AR[5];
    unsigned keepm = 0;
    #pragma unroll
    for (int s5=0; s5<5; ++s5){
      int j = lane + 64*s5;
      if (j < KTOP){
        X1[s5]=bxl[j][0]; Y1[s5]=bxl[j][1]; X2[s5]=bxl[j][2]; Y2[s5]=bxl[j][3];
        AR[s5]=areal[j];
        keepm |= (1u << s5);
      } else { X1[s5]=0;Y1[s5]=0;X2[s5]=0;Y2[s5]=0;AR[s5]=0; }
    }
    for (int i=0;i<KTOP;i++){
      const int iw = i & 63, is = i >> 6;           // wave-uniform
      unsigned km = __shfl(keepm, iw);
      if ((km >> is) & 1u){
        float sx1 = (is==0)?X1[0]:(is==1)?X1[1]:(is==2)?X1[2]:(is==3)?X1[3]:X1[4];
        float sy1 = (is==0)?Y1[0]:(is==1)?Y1[1]:(is==2)?Y1[2]:(is==3)?Y1[3]:Y1[4];
        float sx2 = (is==0)?X2[0]:(is==1)?X2[1]:(is==2)?X2[2]:(is==3)?X2[3]:X2[4];
        float sy2 = (is==0)?Y2[0]:(is==1)?Y2[1]:(is==2)?Y2[2]:(is==3)?Y2[3]:Y2[4];
        float sa  = (is==0)?AR[0]:(is==1)?AR[1]:(is==2)?AR[2]:(is==3)?AR[3]:AR[4];
        float bx1=__shfl(sx1,iw), by1=__shfl(sy1,iw);
        float bx2=__shfl(sx2,iw), by2=__shfl(sy2,iw);
        float ba =__shfl(sa ,iw);
        #pragma unroll
        for (int s5=0; s5<5; ++s5){
          int j = lane + 64*s5;
          if (((keepm >> s5) & 1u) && j > i){
            float ix1=fmaxf(bx1,X1[s5]);
            float iy1=fmaxf(by1,Y1[s5]);
            float ix2=fminf(bx2,X2[s5]);
            float iy2=fminf(by2,Y2[s5]);
            float inter=fmaxf(ix2-ix1,0.0f)*fmaxf(iy2-iy1,0.0f);
            float iou = inter/(ba+AR[s5]-inter+1e-7f);
            if (iou > 0.5f) keepm &= ~(1u << s5);
          }
        }
      }
    }
    // ---- write output rows ----
    #pragma unroll
    for (int s5=0; s5<5; ++s5){
      int j = lane + 64*s5;
      if (j < KTOP){
        float scv = selsc[j];
        float kf  = (((keepm >> s5) & 1u) && scv > 0.0f) ? 1.0f : 0.0f;
        float* o = out + ((size_t)b*KTOP + j)*6;
        o[0]=X1[s5]; o[1]=Y1[s5]; o[2]=X2[s5]; o[3]=Y2[s5];
        o[4]=scv; o[5]=kf;
      }
    }
  }
}

extern "C" void kernel_launch(void* const* d_in, const int* in_sizes, int n_in,
                              void* d_out, int out_size, void* d_ws, size_t ws_size,
                              hipStream_t stream) {
  const float* x  = (const float*)d_in[0];
  const float* W1 = (const float*)d_in[1];
  const float* b1 = (const float*)d_in[2];
  const float* W2 = (const float*)d_in[3];
  const float* b2 = (const float*)d_in[4];
  const float* W3 = (const float*)d_in[5];
  const float* b3 = (const float*)d_in[6];
  const float* Wh = (const float*)d_in[7];
  const float* bh = (const float*)d_in[8];
  float* out = (float*)d_out;
  float* ws  = (float*)d_ws;

  float* f1     = ws;               // 16x16x320x320 = 26,214,400
  float* f2     = ws + 26214400;    // 16x32x160x160 = 13,107,200
  float* f3     = ws;               // reuse f1: 16x64x80x80
  float* boxes  = ws + 26214400;    // reuse f2: 16x19200x4
  float* scores = boxes + 1228800;  // 16x19200

  conv3x3s2_tiled<3,16,16,3,640,320><<<20*20*BATCH*1, 256, 0, stream>>>(x,  W1, b1, f1);
  conv3x3s2_tiled<16,32,32,8,320,160><<<10*10*BATCH*1, 256, 0, stream>>>(f1, W2, b2, f2);
  conv3x3s2_tiled<32,64,32,8,160,80><<<5*5*BATCH*2, 256, 0, stream>>>(f2, W3, b3, f3);

  decode_kernel<<<(BATCH*NANCH*GRID*GRID+255)/256, 256, 0, stream>>>(f3, Wh, bh, boxes, scores);
  topk_nms_kernel<<<BATCH, 1024, 0, stream>>>(boxes, scores, out);
}

// Round 4
// 744.747 us; speedup vs baseline: 4.1964x; 1.0027x over previous
//
#include <hip/hip_runtime.h>
#include <math.h>

#define BATCH 16
#define GRID  80
#define NANCH 3
#define KTOP  300
#define NBOX  (NANCH*GRID*GRID)   // 19200
#define SORT_CAP 8192

__device__ __forceinline__ float sigmoidf_(float x){ return 1.0f/(1.0f+expf(-x)); }

// ---------------- tiled 3x3 stride-2 conv + SiLU ----------------
template<int CIN, int COUT, int COUT_TILE, int IC_CHUNK, int HIN, int HOUT>
__global__ __launch_bounds__(256) void conv3x3s2_tiled(
    const float* __restrict__ in, const float* __restrict__ w,
    const float* __restrict__ bias, float* __restrict__ out)
{
  constexpr int TILES = HOUT/16;
  constexpr int TE = 33*33; // 1089 elements per channel tile
  __shared__ float lds[IC_CHUNK*TE];
  const int t  = threadIdx.x;
  const int tx = t & 15, ty = t >> 4;
  int blk = blockIdx.x;
  const int bx = blk % TILES; blk /= TILES;
  const int by = blk % TILES; blk /= TILES;
  const int b  = blk % BATCH; blk /= BATCH;
  const int ocg= blk;
  const int ox = bx*16 + tx, oy = by*16 + ty;
  const int ix0 = bx*32, iy0 = by*32;

  float acc[COUT_TILE];
  #pragma unroll
  for (int oc=0; oc<COUT_TILE; ++oc) acc[oc] = bias[ocg*COUT_TILE+oc];

  for (int c0=0; c0<CIN; c0+=IC_CHUNK){
    __syncthreads();
    for (int i=t; i<IC_CHUNK*TE; i+=256){
      int c = i/TE, r = i - c*TE;
      int yy = r/33, xx = r - yy*33;
      int iy = iy0+yy, ix = ix0+xx;
      float v = 0.0f;
      if (iy < HIN && ix < HIN)
        v = in[((size_t)(b*CIN + c0+c)*HIN + iy)*HIN + ix];
      lds[i] = v;
    }
    __syncthreads();
    for (int ic=0; ic<IC_CHUNK; ++ic){
      const float* lp = lds + ic*TE + (2*ty)*33 + 2*tx;
      float v[9];
      #pragma unroll
      for (int ky=0;ky<3;ky++)
        #pragma unroll
        for (int kx=0;kx<3;kx++)
          v[ky*3+kx] = lp[ky*33+kx];
      const float* wp = w + ((size_t)(ocg*COUT_TILE)*CIN + (c0+ic))*9;
      #pragma unroll
      for (int oc=0; oc<COUT_TILE; ++oc){
        const float* wo = wp + (size_t)oc*CIN*9;
        #pragma unroll
        for (int k=0;k<9;k++)
          acc[oc] += v[k]*wo[k];
      }
    }
  }

  #pragma unroll
  for (int oc=0; oc<COUT_TILE; ++oc){
    float z = acc[oc];
    float s = 1.0f/(1.0f+expf(-z));
    out[((size_t)(b*COUT + ocg*COUT_TILE+oc)*HOUT + oy)*HOUT + ox] = z*s;
  }
}

// ---------------- 1x1 head (6 needed channels) + sigmoid + decode ----------------
__global__ __launch_bounds__(256) void decode_kernel(
    const float* __restrict__ f3, const float* __restrict__ Wh,
    const float* __restrict__ bh, float* __restrict__ boxes,
    float* __restrict__ scores)
{
  int idx = blockIdx.x*256 + threadIdx.x;
  const int total = BATCH*NANCH*GRID*GRID;
  if (idx >= total) return;
  int gx = idx % GRID;
  int gy = (idx/GRID)%GRID;
  int a  = (idx/(GRID*GRID))%NANCH;
  int b  = idx/(GRID*GRID*NANCH);
  const float aw[3] = {4.0f, 8.0f, 13.0f};
  const float ah[3] = {5.0f, 10.0f, 16.0f};
  const int   chs[6] = {0,1,2,3,4,15};
  const float* f = f3 + (size_t)b*64*GRID*GRID + (size_t)gy*GRID + gx;
  float acc[6];
  #pragma unroll
  for (int j=0;j<6;j++) acc[j] = bh[a*16 + chs[j]];
  for (int ic=0; ic<64; ++ic){
    float v = f[(size_t)ic*GRID*GRID];
    #pragma unroll
    for (int j=0;j<6;j++) acc[j] += v * Wh[(size_t)(a*16+chs[j])*64 + ic];
  }
  float p0 = sigmoidf_(acc[0]);
  float p1 = sigmoidf_(acc[1]);
  float p2 = sigmoidf_(acc[2]);
  float p3 = sigmoidf_(acc[3]);
  float p4 = sigmoidf_(acc[4]);
  float p15= sigmoidf_(acc[5]);
  float cx = (p0*2.0f - 0.5f + (float)gx)*8.0f;
  float cy = (p1*2.0f - 0.5f + (float)gy)*8.0f;
  float ww = p2*2.0f; ww = ww*ww*aw[a];
  float hh = p3*2.0f; hh = hh*hh*ah[a];
  float sc = p4*p15;
  sc = (sc > 0.5f) ? sc : 0.0f;
  int bi = a*GRID*GRID + gy*GRID + gx;
  float* bo = boxes + ((size_t)b*NBOX + bi)*4;
  bo[0] = cx - ww*0.5f;
  bo[1] = cy - hh*0.5f;
  bo[2] = cx + ww*0.5f;
  bo[3] = cy + hh*0.5f;
  scores[(size_t)b*NBOX + bi] = sc;
}

// ---------------- kernel A: compact + bitonic-sort top-K + gather ----------------
// writes nmsbuf[b][j][6] = {x1,y1,x2,y2,score,area}
__global__ __launch_bounds__(1024) void topk_kernel(
    const float* __restrict__ boxes, const float* __restrict__ scores,
    float* __restrict__ nmsbuf)
{
  __shared__ unsigned long long keys[SORT_CAP];  // 64 KB
  __shared__ int   cntM;
  __shared__ int   sel[KTOP];
  __shared__ float selsc[KTOP];
  __shared__ int   wsum[16];
  __shared__ float rs[16];
  __shared__ int   ri[16];
  __shared__ unsigned clm[(NBOX+31)/32];         // fallback claimed bitmask

  const int b = blockIdx.x;
  const int t = threadIdx.x;
  const int lane = t & 63, wv = t >> 6;
  const float* scp = scores + (size_t)b*NBOX;

  if (t == 0) cntM = 0;
  __syncthreads();

  // compact positives: key = (score_bits<<32) | ~idx  (stable desc order)
  for (int i=t; i<NBOX; i+=1024){
    float v = scp[i];
    if (v > 0.0f){
      int p = atomicAdd(&cntM, 1);
      if (p < SORT_CAP)
        keys[p] = ((unsigned long long)__float_as_uint(v) << 32)
                | (unsigned)(0xFFFFFFFFu - (unsigned)i);
    }
  }
  __syncthreads();
  const int M = cntM;

  if (M <= SORT_CAP){
    int P = 64; while (P < M) P <<= 1;
    for (int i=t; i<P; i+=1024) if (i >= M) keys[i] = 0ULL;
    __syncthreads();
    for (int k=2; k<=P; k<<=1){
      for (int j=k>>1; j>0; j>>=1){
        for (int i=t; i<P; i+=1024){
          int ixj = i ^ j;
          if (ixj > i){
            unsigned long long a = keys[i], c = keys[ixj];
            bool up = ((i & k) == 0);
            if (up ? (a < c) : (a > c)){ keys[i] = c; keys[ixj] = a; }
          }
        }
        __syncthreads();
      }
    }
    const int top = (M < KTOP) ? M : KTOP;
    if (t < top){
      unsigned long long kk = keys[t];
      selsc[t] = __uint_as_float((unsigned)(kk >> 32));
      sel[t]   = (int)(0xFFFFFFFFu - (unsigned)(kk & 0xFFFFFFFFu));
    }
    if (M < KTOP){
      const int need = KTOP - M;
      const int C = (NBOX + 1023)/1024;   // 19
      int lo = t*C, hi = lo+C; if (hi > NBOX) hi = NBOX; if (lo > NBOX) lo = NBOX;
      int zc = 0;
      for (int i=lo;i<hi;i++) if (scp[i] <= 0.0f) zc++;
      int v = zc;
      #pragma unroll
      for (int off=1; off<64; off<<=1){
        int n = __shfl_up(v, off);
        if (lane >= off) v += n;
      }
      if (lane == 63) wsum[wv] = v;
      __syncthreads();
      if (t == 0){
        int a = 0;
        for (int w=0; w<16; w++){ int tmp = wsum[w]; wsum[w] = a; a += tmp; }
      }
      __syncthreads();
      int r = wsum[wv] + v - zc;
      for (int i=lo;i<hi;i++){
        if (scp[i] <= 0.0f){
          if (r < need){ sel[M+r] = i; selsc[M+r] = 0.0f; }
          r++;
        }
      }
    }
    __syncthreads();
  } else {
    // fallback: exact argmax passes with claimed bitmask
    for (int i=t; i<(NBOX+31)/32; i+=1024) clm[i] = 0u;
    __syncthreads();
    for (int k=0;k<KTOP;k++){
      float best = -2.0f; int bi = NBOX;
      for (int i=t;i<NBOX;i+=1024){
        if (!((clm[i>>5] >> (i&31)) & 1u)){
          float v = scp[i];
          if (v > best){ best=v; bi=i; }
        }
      }
      #pragma unroll
      for (int off=32; off>0; off>>=1){
        float ov = __shfl_down(best, off);
        int   oi = __shfl_down(bi,   off);
        if (ov > best || (ov == best && oi < bi)){ best=ov; bi=oi; }
      }
      if (lane == 0){ rs[wv]=best; ri[wv]=bi; }
      __syncthreads();
      if (t == 0){
        for (int w=1; w<16; w++)
          if (rs[w] > best || (rs[w] == best && ri[w] < bi)){ best=rs[w]; bi=ri[w]; }
        sel[k]=bi; selsc[k]=best; clm[bi>>5] |= (1u << (bi&31));
      }
      __syncthreads();
    }
  }

  if (t < KTOP){
    const float* bp = boxes + ((size_t)b*NBOX + sel[t])*4;
    float x1=bp[0], y1=bp[1], x2=bp[2], y2=bp[3];
    float* o = nmsbuf + ((size_t)b*KTOP + t)*6;
    o[0]=x1; o[1]=y1; o[2]=x2; o[3]=y2;
    o[4]=selsc[t];
    o[5]=fmaxf(x2-x1,0.0f)*fmaxf(y2-y1,0.0f);
  }
}

// ---------------- kernel B: single-wave register NMS + final write ----------------
__global__ __launch_bounds__(64) void nms_kernel(
    const float* __restrict__ nmsbuf, float* __restrict__ out)
{
  const int b = blockIdx.x;
  const int lane = threadIdx.x;
  float X1[5],Y1[5],X2[5],Y2[5],AR[5],SC[5];
  unsigned keepm = 0;
  #pragma unroll
  for (int s5=0; s5<5; ++s5){
    int j = lane + 64*s5;
    if (j < KTOP){
      const float* p = nmsbuf + ((size_t)b*KTOP + j)*6;
      X1[s5]=p[0]; Y1[s5]=p[1]; X2[s5]=p[2]; Y2[s5]=p[3];
      SC[s5]=p[4]; AR[s5]=p[5];
      keepm |= (1u << s5);
    } else { X1[s5]=0;Y1[s5]=0;X2[s5]=0;Y2[s5]=0;AR[s5]=0;SC[s5]=0; }
  }
  for (int i=0;i<KTOP;i++){
    const int iw = i & 63, is = i >> 6;           // wave-uniform
    unsigned km = __shfl(keepm, iw);
    if ((km >> is) & 1u){
      float sx1 = (is==0)?X1[0]:(is==1)?X1[1]:(is==2)?X1[2]:(is==3)?X1[3]:X1[4];
      float sy1 = (is==0)?Y1[0]:(is==1)?Y1[1]:(is==2)?Y1[2]:(is==3)?Y1[3]:Y1[4];
      float sx2 = (is==0)?X2[0]:(is==1)?X2[1]:(is==2)?X2[2]:(is==3)?X2[3]:X2[4];
      float sy2 = (is==0)?Y2[0]:(is==1)?Y2[1]:(is==2)?Y2[2]:(is==3)?Y2[3]:Y2[4];
      float sa  = (is==0)?AR[0]:(is==1)?AR[1]:(is==2)?AR[2]:(is==3)?AR[3]:AR[4];
      float bx1=__shfl(sx1,iw), by1=__shfl(sy1,iw);
      float bx2=__shfl(sx2,iw), by2=__shfl(sy2,iw);
      float ba =__shfl(sa ,iw);
      #pragma unroll
      for (int s5=0; s5<5; ++s5){
        int j = lane + 64*s5;
        if (((keepm >> s5) & 1u) && j > i){
          float ix1=fmaxf(bx1,X1[s5]);
          float iy1=fmaxf(by1,Y1[s5]);
          float ix2=fminf(bx2,X2[s5]);
          float iy2=fminf(by2,Y2[s5]);
          float inter=fmaxf(ix2-ix1,0.0f)*fmaxf(iy2-iy1,0.0f);
          float iou = inter/(ba+AR[s5]-inter+1e-7f);
          if (iou > 0.5f) keepm &= ~(1u << s5);
        }
      }
    }
  }
  #pragma unroll
  for (int s5=0; s5<5; ++s5){
    int j = lane + 64*s5;
    if (j < KTOP){
      float scv = SC[s5];
      float kf  = (((keepm >> s5) & 1u) && scv > 0.0f) ? 1.0f : 0.0f;
      float* o = out + ((size_t)b*KTOP + j)*6;
      o[0]=X1[s5]; o[1]=Y1[s5]; o[2]=X2[s5]; o[3]=Y2[s5];
      o[4]=scv; o[5]=kf;
    }
  }
}

extern "C" void kernel_launch(void* const* d_in, const int* in_sizes, int n_in,
                              void* d_out, int out_size, void* d_ws, size_t ws_size,
                              hipStream_t stream) {
  const float* x  = (const float*)d_in[0];
  const float* W1 = (const float*)d_in[1];
  const float* b1 = (const float*)d_in[2];
  const float* W2 = (const float*)d_in[3];
  const float* b2 = (const float*)d_in[4];
  const float* W3 = (const float*)d_in[5];
  const float* b3 = (const float*)d_in[6];
  const float* Wh = (const float*)d_in[7];
  const float* bh = (const float*)d_in[8];
  float* out = (float*)d_out;
  float* ws  = (float*)d_ws;

  float* f1     = ws;               // 16x16x320x320 = 26,214,400
  float* f2     = ws + 26214400;    // 16x32x160x160 = 13,107,200
  float* f3     = ws;               // reuse f1: 16x64x80x80
  float* boxes  = ws + 26214400;    // reuse f2: 16x19200x4
  float* scores = boxes + 1228800;  // 16x19200
  float* nmsbuf = scores + 307200;  // 16x300x6 = 28,800

  conv3x3s2_tiled<3,16,16,3,640,320><<<20*20*BATCH*1, 256, 0, stream>>>(x,  W1, b1, f1);
  conv3x3s2_tiled<16,32,32,8,320,160><<<10*10*BATCH*1, 256, 0, stream>>>(f1, W2, b2, f2);
  conv3x3s2_tiled<32,64,32,8,160,80><<<5*5*BATCH*2, 256, 0, stream>>>(f2, W3, b3, f3);

  decode_kernel<<<(BATCH*NANCH*GRID*GRID+255)/256, 256, 0, stream>>>(f3, Wh, bh, boxes, scores);
  topk_kernel<<<BATCH, 1024, 0, stream>>>(boxes, scores, nmsbuf);
  nms_kernel<<<BATCH, 64, 0, stream>>>(nmsbuf, out);
}

// Round 5
// 558.761 us; speedup vs baseline: 5.5931x; 1.3329x over previous
//
#include <hip/hip_runtime.h>
#include <math.h>

#define BATCH 16
#define GRID  80
#define NANCH 3
#define KTOP  300
#define NBOX  (NANCH*GRID*GRID)   // 19200
#define SORT_CAP 8192

__device__ __forceinline__ float sigmoidf_(float x){ return 1.0f/(1.0f+expf(-x)); }

// ---------------- tiled 3x3 stride-2 conv + SiLU ----------------
template<int CIN, int COUT, int COUT_TILE, int IC_CHUNK, int HIN, int HOUT>
__global__ __launch_bounds__(256) void conv3x3s2_tiled(
    const float* __restrict__ in, const float* __restrict__ w,
    const float* __restrict__ bias, float* __restrict__ out)
{
  constexpr int TILES = HOUT/16;
  constexpr int TE = 33*33; // 1089 elements per channel tile
  __shared__ float lds[IC_CHUNK*TE];
  const int t  = threadIdx.x;
  const int tx = t & 15, ty = t >> 4;
  int blk = blockIdx.x;
  const int bx = blk % TILES; blk /= TILES;
  const int by = blk % TILES; blk /= TILES;
  const int b  = blk % BATCH; blk /= BATCH;
  const int ocg= blk;
  const int ox = bx*16 + tx, oy = by*16 + ty;
  const int ix0 = bx*32, iy0 = by*32;

  float acc[COUT_TILE];
  #pragma unroll
  for (int oc=0; oc<COUT_TILE; ++oc) acc[oc] = bias[ocg*COUT_TILE+oc];

  for (int c0=0; c0<CIN; c0+=IC_CHUNK){
    __syncthreads();
    for (int i=t; i<IC_CHUNK*TE; i+=256){
      int c = i/TE, r = i - c*TE;
      int yy = r/33, xx = r - yy*33;
      int iy = iy0+yy, ix = ix0+xx;
      float v = 0.0f;
      if (iy < HIN && ix < HIN)
        v = in[((size_t)(b*CIN + c0+c)*HIN + iy)*HIN + ix];
      lds[i] = v;
    }
    __syncthreads();
    for (int ic=0; ic<IC_CHUNK; ++ic){
      const float* lp = lds + ic*TE + (2*ty)*33 + 2*tx;
      float v[9];
      #pragma unroll
      for (int ky=0;ky<3;ky++)
        #pragma unroll
        for (int kx=0;kx<3;kx++)
          v[ky*3+kx] = lp[ky*33+kx];
      const float* wp = w + ((size_t)(ocg*COUT_TILE)*CIN + (c0+ic))*9;
      #pragma unroll
      for (int oc=0; oc<COUT_TILE; ++oc){
        const float* wo = wp + (size_t)oc*CIN*9;
        #pragma unroll
        for (int k=0;k<9;k++)
          acc[oc] += v[k]*wo[k];
      }
    }
  }

  #pragma unroll
  for (int oc=0; oc<COUT_TILE; ++oc){
    float z = acc[oc];
    float s = 1.0f/(1.0f+expf(-z));
    out[((size_t)(b*COUT + ocg*COUT_TILE+oc)*HOUT + oy)*HOUT + ox] = z*s;
  }
}

// ---------------- 1x1 head (6 needed channels) + sigmoid + decode ----------------
__global__ __launch_bounds__(256) void decode_kernel(
    const float* __restrict__ f3, const float* __restrict__ Wh,
    const float* __restrict__ bh, float* __restrict__ boxes,
    float* __restrict__ scores)
{
  int idx = blockIdx.x*256 + threadIdx.x;
  const int total = BATCH*NANCH*GRID*GRID;
  if (idx >= total) return;
  int gx = idx % GRID;
  int gy = (idx/GRID)%GRID;
  int a  = (idx/(GRID*GRID))%NANCH;
  int b  = idx/(GRID*GRID*NANCH);
  const float aw[3] = {4.0f, 8.0f, 13.0f};
  const float ah[3] = {5.0f, 10.0f, 16.0f};
  const int   chs[6] = {0,1,2,3,4,15};
  const float* f = f3 + (size_t)b*64*GRID*GRID + (size_t)gy*GRID + gx;
  float acc[6];
  #pragma unroll
  for (int j=0;j<6;j++) acc[j] = bh[a*16 + chs[j]];
  for (int ic=0; ic<64; ++ic){
    float v = f[(size_t)ic*GRID*GRID];
    #pragma unroll
    for (int j=0;j<6;j++) acc[j] += v * Wh[(size_t)(a*16+chs[j])*64 + ic];
  }
  float p0 = sigmoidf_(acc[0]);
  float p1 = sigmoidf_(acc[1]);
  float p2 = sigmoidf_(acc[2]);
  float p3 = sigmoidf_(acc[3]);
  float p4 = sigmoidf_(acc[4]);
  float p15= sigmoidf_(acc[5]);
  float cx = (p0*2.0f - 0.5f + (float)gx)*8.0f;
  float cy = (p1*2.0f - 0.5f + (float)gy)*8.0f;
  float ww = p2*2.0f; ww = ww*ww*aw[a];
  float hh = p3*2.0f; hh = hh*hh*ah[a];
  float sc = p4*p15;
  sc = (sc > 0.5f) ? sc : 0.0f;
  int bi = a*GRID*GRID + gy*GRID + gx;
  float* bo = boxes + ((size_t)b*NBOX + bi)*4;
  bo[0] = cx - ww*0.5f;
  bo[1] = cy - hh*0.5f;
  bo[2] = cx + ww*0.5f;
  bo[3] = cy + hh*0.5f;
  scores[(size_t)b*NBOX + bi] = sc;
}

// ---------------- kernel A: compact + bitonic-sort top-K + gather ----------------
// writes nmsbuf[b][j][6] = {x1,y1,x2,y2,score,area}; mcnt[b] = #positives
__global__ __launch_bounds__(1024) void topk_kernel(
    const float* __restrict__ boxes, const float* __restrict__ scores,
    float* __restrict__ nmsbuf, int* __restrict__ mcnt)
{
  __shared__ unsigned long long keys[SORT_CAP];  // 64 KB
  __shared__ int   cntM;
  __shared__ int   sel[KTOP];
  __shared__ float selsc[KTOP];
  __shared__ int   wsum[16];
  __shared__ float rs[16];
  __shared__ int   ri[16];
  __shared__ unsigned clm[(NBOX+31)/32];         // fallback claimed bitmask

  const int b = blockIdx.x;
  const int t = threadIdx.x;
  const int lane = t & 63, wv = t >> 6;
  const float* scp = scores + (size_t)b*NBOX;

  if (t == 0) cntM = 0;
  __syncthreads();

  // compact positives: key = (score_bits<<32) | ~idx  (stable desc order)
  for (int i=t; i<NBOX; i+=1024){
    float v = scp[i];
    if (v > 0.0f){
      int p = atomicAdd(&cntM, 1);
      if (p < SORT_CAP)
        keys[p] = ((unsigned long long)__float_as_uint(v) << 32)
                | (unsigned)(0xFFFFFFFFu - (unsigned)i);
    }
  }
  __syncthreads();
  const int M = cntM;
  if (t == 0) mcnt[b] = M;

  if (M <= SORT_CAP){
    int P = 64; while (P < M) P <<= 1;
    for (int i=t; i<P; i+=1024) if (i >= M) keys[i] = 0ULL;
    __syncthreads();
    for (int k=2; k<=P; k<<=1){
      for (int j=k>>1; j>0; j>>=1){
        for (int i=t; i<P; i+=1024){
          int ixj = i ^ j;
          if (ixj > i){
            unsigned long long a = keys[i], c = keys[ixj];
            bool up = ((i & k) == 0);
            if (up ? (a < c) : (a > c)){ keys[i] = c; keys[ixj] = a; }
          }
        }
        __syncthreads();
      }
    }
    const int top = (M < KTOP) ? M : KTOP;
    if (t < top){
      unsigned long long kk = keys[t];
      selsc[t] = __uint_as_float((unsigned)(kk >> 32));
      sel[t]   = (int)(0xFFFFFFFFu - (unsigned)(kk & 0xFFFFFFFFu));
    }
    if (M < KTOP){
      const int need = KTOP - M;
      const int C = (NBOX + 1023)/1024;   // 19
      int lo = t*C, hi = lo+C; if (hi > NBOX) hi = NBOX; if (lo > NBOX) lo = NBOX;
      int zc = 0;
      for (int i=lo;i<hi;i++) if (scp[i] <= 0.0f) zc++;
      int v = zc;
      #pragma unroll
      for (int off=1; off<64; off<<=1){
        int n = __shfl_up(v, off);
        if (lane >= off) v += n;
      }
      if (lane == 63) wsum[wv] = v;
      __syncthreads();
      if (t == 0){
        int a = 0;
        for (int w=0; w<16; w++){ int tmp = wsum[w]; wsum[w] = a; a += tmp; }
      }
      __syncthreads();
      int r = wsum[wv] + v - zc;
      for (int i=lo;i<hi;i++){
        if (scp[i] <= 0.0f){
          if (r < need){ sel[M+r] = i; selsc[M+r] = 0.0f; }
          r++;
        }
      }
    }
    __syncthreads();
  } else {
    // fallback: exact argmax passes with claimed bitmask
    for (int i=t; i<(NBOX+31)/32; i+=1024) clm[i] = 0u;
    __syncthreads();
    for (int k=0;k<KTOP;k++){
      float best = -2.0f; int bi = NBOX;
      for (int i=t;i<NBOX;i+=1024){
        if (!((clm[i>>5] >> (i&31)) & 1u)){
          float v = scp[i];
          if (v > best){ best=v; bi=i; }
        }
      }
      #pragma unroll
      for (int off=32; off>0; off>>=1){
        float ov = __shfl_down(best, off);
        int   oi = __shfl_down(bi,   off);
        if (ov > best || (ov == best && oi < bi)){ best=ov; bi=oi; }
      }
      if (lane == 0){ rs[wv]=best; ri[wv]=bi; }
      __syncthreads();
      if (t == 0){
        for (int w=1; w<16; w++)
          if (rs[w] > best || (rs[w] == best && ri[w] < bi)){ best=rs[w]; bi=ri[w]; }
        sel[k]=bi; selsc[k]=best; clm[bi>>5] |= (1u << (bi&31));
      }
      __syncthreads();
    }
  }

  if (t < KTOP){
    const float* bp = boxes + ((size_t)b*NBOX + sel[t])*4;
    float x1=bp[0], y1=bp[1], x2=bp[2], y2=bp[3];
    float* o = nmsbuf + ((size_t)b*KTOP + t)*6;
    o[0]=x1; o[1]=y1; o[2]=x2; o[3]=y2;
    o[4]=selsc[t];
    o[5]=fmaxf(x2-x1,0.0f)*fmaxf(y2-y1,0.0f);
  }
}

// ---------------- kernel B: single-wave register NMS + final write ----------------
// launch_bounds(64,1): 1 wave/EU -> full 512-VGPR budget, no spills.
// NMS loop runs only i < min(M,KTOP): slots >= M have score 0, so their keep
// flag is forced to 0 by (score>0) and they cannot change any visible output.
__global__ __launch_bounds__(64, 1) void nms_kernel(
    const float* __restrict__ nmsbuf, const int* __restrict__ mcnt,
    float* __restrict__ out)
{
  const int b = blockIdx.x;
  const int lane = threadIdx.x;
  int Mtop = mcnt[b]; if (Mtop > KTOP) Mtop = KTOP;
  float X1[5],Y1[5],X2[5],Y2[5],AR[5],SC[5];
  unsigned keepm = 0;
  #pragma unroll
  for (int s5=0; s5<5; ++s5){
    int j = lane + 64*s5;
    if (j < KTOP){
      const float* p = nmsbuf + ((size_t)b*KTOP + j)*6;
      X1[s5]=p[0]; Y1[s5]=p[1]; X2[s5]=p[2]; Y2[s5]=p[3];
      SC[s5]=p[4]; AR[s5]=p[5];
      keepm |= (1u << s5);
    } else { X1[s5]=0;Y1[s5]=0;X2[s5]=0;Y2[s5]=0;AR[s5]=0;SC[s5]=0; }
  }
  for (int i=0;i<Mtop;i++){
    const int iw = i & 63, is = i >> 6;           // wave-uniform
    unsigned km = __shfl(keepm, iw);
    if ((km >> is) & 1u){
      float sx1 = (is==0)?X1[0]:(is==1)?X1[1]:(is==2)?X1[2]:(is==3)?X1[3]:X1[4];
      float sy1 = (is==0)?Y1[0]:(is==1)?Y1[1]:(is==2)?Y1[2]:(is==3)?Y1[3]:Y1[4];
      float sx2 = (is==0)?X2[0]:(is==1)?X2[1]:(is==2)?X2[2]:(is==3)?X2[3]:X2[4];
      float sy2 = (is==0)?Y2[0]:(is==1)?Y2[1]:(is==2)?Y2[2]:(is==3)?Y2[3]:Y2[4];
      float sa  = (is==0)?AR[0]:(is==1)?AR[1]:(is==2)?AR[2]:(is==3)?AR[3]:AR[4];
      float bx1=__shfl(sx1,iw), by1=__shfl(sy1,iw);
      float bx2=__shfl(sx2,iw), by2=__shfl(sy2,iw);
      float ba =__shfl(sa ,iw);
      #pragma unroll
      for (int s5=0; s5<5; ++s5){
        int j = lane + 64*s5;
        if (((keepm >> s5) & 1u) && j > i){
          float ix1=fmaxf(bx1,X1[s5]);
          float iy1=fmaxf(by1,Y1[s5]);
          float ix2=fminf(bx2,X2[s5]);
          float iy2=fminf(by2,Y2[s5]);
          float inter=fmaxf(ix2-ix1,0.0f)*fmaxf(iy2-iy1,0.0f);
          float iou = inter/(ba+AR[s5]-inter+1e-7f);
          if (iou > 0.5f) keepm &= ~(1u << s5);
        }
      }
    }
  }
  #pragma unroll
  for (int s5=0; s5<5; ++s5){
    int j = lane + 64*s5;
    if (j < KTOP){
      float scv = SC[s5];
      float kf  = (((keepm >> s5) & 1u) && scv > 0.0f) ? 1.0f : 0.0f;
      float* o = out + ((size_t)b*KTOP + j)*6;
      o[0]=X1[s5]; o[1]=Y1[s5]; o[2]=X2[s5]; o[3]=Y2[s5];
      o[4]=scv; o[5]=kf;
    }
  }
}

extern "C" void kernel_launch(void* const* d_in, const int* in_sizes, int n_in,
                              void* d_out, int out_size, void* d_ws, size_t ws_size,
                              hipStream_t stream) {
  const float* x  = (const float*)d_in[0];
  const float* W1 = (const float*)d_in[1];
  const float* b1 = (const float*)d_in[2];
  const float* W2 = (const float*)d_in[3];
  const float* b2 = (const float*)d_in[4];
  const float* W3 = (const float*)d_in[5];
  const float* b3 = (const float*)d_in[6];
  const float* Wh = (const float*)d_in[7];
  const float* bh = (const float*)d_in[8];
  float* out = (float*)d_out;
  float* ws  = (float*)d_ws;

  float* f1     = ws;               // 16x16x320x320 = 26,214,400
  float* f2     = ws + 26214400;    // 16x32x160x160 = 13,107,200
  float* f3     = ws;               // reuse f1: 16x64x80x80
  float* boxes  = ws + 26214400;    // reuse f2: 16x19200x4
  float* scores = boxes + 1228800;  // 16x19200
  float* nmsbuf = scores + 307200;  // 16x300x6 = 28,800
  int*   mcnt   = (int*)(nmsbuf + 28800);

  conv3x3s2_tiled<3,16,16,3,640,320><<<20*20*BATCH*1, 256, 0, stream>>>(x,  W1, b1, f1);
  conv3x3s2_tiled<16,32,32,8,320,160><<<10*10*BATCH*1, 256, 0, stream>>>(f1, W2, b2, f2);
  conv3x3s2_tiled<32,64,32,8,160,80><<<5*5*BATCH*2, 256, 0, stream>>>(f2, W3, b3, f3);

  decode_kernel<<<(BATCH*NANCH*GRID*GRID+255)/256, 256, 0, stream>>>(f3, Wh, bh, boxes, scores);
  topk_kernel<<<BATCH, 1024, 0, stream>>>(boxes, scores, nmsbuf, mcnt);
  nms_kernel<<<BATCH, 64, 0, stream>>>(nmsbuf, mcnt, out);
}